// Round 3
// baseline (317.090 us; speedup 1.0000x reference)
//
#include <hip/hip_runtime.h>
#include <hip/hip_bf16.h>
#include <hip/hip_fp16.h>

typedef _Float16 half8 __attribute__((ext_vector_type(8)));
typedef _Float16 half4_t __attribute__((ext_vector_type(4)));
typedef _Float16 h2 __attribute__((ext_vector_type(2)));
typedef float f32x4 __attribute__((ext_vector_type(4)));
typedef unsigned int u32;

#define NEG_SLOPE 0.2f
#define SELU_SCALE 1.0507009873554805f
#define SELU_ALPHA 1.6732632423543772f
#define LOG2E 1.4426950408889634f

#if __has_builtin(__builtin_amdgcn_fdot2)
#define FDOT2(a, b, c) __builtin_amdgcn_fdot2((a), (b), (c), false)
#else
static __device__ inline float FDOT2(h2 a, h2 b, float c) {
    return c + (float)a[0] * (float)b[0] + (float)a[1] * (float)b[1];
}
#endif

static __device__ inline h2 h2max(h2 a, h2 b) {
#if __has_builtin(__builtin_elementwise_max)
    return __builtin_elementwise_max(a, b);
#else
    h2 r; r[0] = a[0] > b[0] ? a[0] : b[0]; r[1] = a[1] > b[1] ? a[1] : b[1]; return r;
#endif
}

// ---------------- GEMM: glr[n][c] = x[n][:] @ Wcat[:][c], c in [0,768)
__global__ __launch_bounds__(256) void gemm_kernel(
    const float* __restrict__ x, const float* __restrict__ Wl,
    const float* __restrict__ Wr, _Float16* __restrict__ glr, int n_nodes)
{
    __shared__ float xs[16 * 68];
    int row0 = blockIdx.x * 16;
    if (row0 >= n_nodes) return;

    {
        int t = threadIdx.x;
        int r = t >> 4, c = (t & 15) * 4;
        int row = row0 + r;
        f32x4 v = (f32x4){0.f, 0.f, 0.f, 0.f};
        if (row < n_nodes) v = *(const f32x4*)(x + (size_t)row * 64 + c);
        *(f32x4*)(xs + r * 68 + c) = v;
    }
    __syncthreads();

    int wid  = threadIdx.x >> 6;
    int lane = threadIdx.x & 63;
    int l15  = lane & 15;
    int kb   = (lane >> 4) * 8;

    half8 a0, a1;
    #pragma unroll
    for (int j = 0; j < 8; j++) {
        a0[j] = (_Float16)xs[l15 * 68 + kb + j];
        a1[j] = (_Float16)xs[l15 * 68 + 32 + kb + j];
    }

    int colbase = wid * 192;
    f32x4 acc[12];
    #pragma unroll
    for (int t = 0; t < 12; t++) acc[t] = (f32x4){0.f, 0.f, 0.f, 0.f};

    #pragma unroll
    for (int t = 0; t < 12; t++) {
        int col = colbase + t * 16 + l15;
        const float* wcol = (col < 384) ? (Wl + col) : (Wr + (col - 384));
        half8 b0, b1;
        #pragma unroll
        for (int j = 0; j < 8; j++) {
            b0[j] = (_Float16)wcol[(size_t)(kb + j) * 384];
            b1[j] = (_Float16)wcol[(size_t)(32 + kb + j) * 384];
        }
        acc[t] = __builtin_amdgcn_mfma_f32_16x16x32_f16(a0, b0, acc[t], 0, 0, 0);
        acc[t] = __builtin_amdgcn_mfma_f32_16x16x32_f16(a1, b1, acc[t], 0, 0, 0);
    }
    #pragma unroll
    for (int t = 0; t < 12; t++) {
        int col = colbase + t * 16 + l15;
        #pragma unroll
        for (int r = 0; r < 4; r++) {
            int row = row0 + (lane >> 4) * 4 + r;
            if (row < n_nodes)
                glr[(size_t)row * 768 + col] = (_Float16)acc[t][r];
        }
    }
}

// ---------------- CSR build ----------------
__global__ void hist_kernel(const int* __restrict__ eidx, int* count, int n_edges) {
    int i = blockIdx.x * blockDim.x + threadIdx.x;
    if (i < n_edges) atomicAdd(&count[eidx[n_edges + i]], 1);  // dst row
}

// local scan of 1024-chunks; element value = count[i] + 1 (self-loop folded in)
__global__ __launch_bounds__(256) void scan_local_kernel(
    const int* __restrict__ count, int* __restrict__ row_ptr,
    int* __restrict__ blksum, int n)
{
    __shared__ int ws[4];
    int blk = blockIdx.x, t = threadIdx.x;
    int base = blk * 1024 + t * 4;
    int a0 = (base + 0 < n) ? count[base + 0] + 1 : 0;
    int a1 = (base + 1 < n) ? count[base + 1] + 1 : 0;
    int a2 = (base + 2 < n) ? count[base + 2] + 1 : 0;
    int a3 = (base + 3 < n) ? count[base + 3] + 1 : 0;
    int tsum = a0 + a1 + a2 + a3;
    int lane = t & 63, wid = t >> 6;
    int s = tsum;
    #pragma unroll
    for (int d = 1; d < 64; d <<= 1) {
        int u = __shfl_up(s, d, 64);
        if (lane >= d) s += u;
    }
    if (lane == 63) ws[wid] = s;
    __syncthreads();
    int woff = 0;
    #pragma unroll
    for (int w = 0; w < 4; w++) if (w < wid) woff += ws[w];
    int excl = woff + s - tsum;
    if (base + 0 < n) row_ptr[base + 0] = excl;
    if (base + 1 < n) row_ptr[base + 1] = excl + a0;
    if (base + 2 < n) row_ptr[base + 2] = excl + a0 + a1;
    if (base + 3 < n) row_ptr[base + 3] = excl + a0 + a1 + a2;
    if (t == 255) blksum[blk] = woff + s;
}

__global__ __launch_bounds__(64) void scan_blk_kernel(
    int* __restrict__ blksum, int* __restrict__ row_ptr, int nblk, int n)
{
    int lane = threadIdx.x;
    int v = (lane < nblk) ? blksum[lane] : 0;
    int s = v;
    #pragma unroll
    for (int d = 1; d < 64; d <<= 1) {
        int u = __shfl_up(s, d, 64);
        if (lane >= d) s += u;
    }
    if (lane < nblk) blksum[lane] = s - v;
    if (lane == 63) row_ptr[n] = s;
}

__global__ void cursor_kernel(int* __restrict__ row_ptr,
                              const int* __restrict__ blksum,
                              int* __restrict__ cursor,
                              int* __restrict__ sorted_src, int n) {
    int i = blockIdx.x * blockDim.x + threadIdx.x;
    if (i < n) {
        int rp = row_ptr[i] + blksum[i >> 10];
        row_ptr[i] = rp;
        cursor[i] = rp + 1;     // slot rp reserved for self-loop
        sorted_src[rp] = i;
    }
}

__global__ void scatter_kernel(const int* __restrict__ eidx, int* cursor,
                               int* sorted_src, int n_edges) {
    int i = blockIdx.x * blockDim.x + threadIdx.x;
    if (i < n_edges) {
        int d = eidx[n_edges + i];
        int s = eidx[i];
        int pos = atomicAdd(&cursor[d], 1);
        sorted_src[pos] = s;
    }
}

// ---------------- Edge phase: one wave per dst node, online softmax ----------
// group g = lane>>4 handles edges (base+2g, base+2g+1); l0 = lane&15 holds
// f = l0*4 + {0..3} for all 6 heads. Logits in log2-domain (att pre-scaled).
__global__ __launch_bounds__(256) void edge_kernel(
    const _Float16* __restrict__ glr,     // [n][768]: gl cols 0..383, gr 384..767
    const int* __restrict__ row_ptr,
    const int* __restrict__ sorted_src,
    const float* __restrict__ att,        // [6][64]
    const float* __restrict__ bias,       // [64]
    float* __restrict__ out, int n_nodes)
{
    int wid  = threadIdx.x >> 6;
    int lane = threadIdx.x & 63;
    int node = blockIdx.x * 4 + wid;
    if (node >= n_nodes) return;
    int g  = lane >> 4;
    int l0 = lane & 15;

    const _Float16 c02 = (_Float16)NEG_SLOPE;

    h2 att_h[12], gr_h[12];
    const _Float16* grp = glr + (size_t)node * 768 + 384;
    #pragma unroll
    for (int h = 0; h < 6; h++) {
        f32x4 av = *(const f32x4*)(att + h * 64 + l0 * 4);
        att_h[2 * h]     = (h2){(_Float16)(av[0] * LOG2E), (_Float16)(av[1] * LOG2E)};
        att_h[2 * h + 1] = (h2){(_Float16)(av[2] * LOG2E), (_Float16)(av[3] * LOG2E)};
        half4_t gvv = *(const half4_t*)(grp + h * 64 + l0 * 4);
        gr_h[2 * h]     = (h2){gvv[0], gvv[1]};
        gr_h[2 * h + 1] = (h2){gvv[2], gvv[3]};
    }

    float m[6], sden[6];
    h2 acc[12];
    #pragma unroll
    for (int h = 0; h < 6; h++) { m[h] = -1e30f; sden[h] = 0.f; }
    #pragma unroll
    for (int q = 0; q < 12; q++) acc[q] = (h2){(_Float16)0.f, (_Float16)0.f};

    int rp = row_ptr[node], re = row_ptr[node + 1];

    half4_t gv0[6], gv1[6];
    {
        int i0 = rp + 2 * g;
        int s0 = (i0     < re) ? sorted_src[i0]     : node;
        int s1 = (i0 + 1 < re) ? sorted_src[i0 + 1] : node;
        const _Float16* p0 = glr + (size_t)s0 * 768;
        const _Float16* p1 = glr + (size_t)s1 * 768;
        #pragma unroll
        for (int h = 0; h < 6; h++) {
            gv0[h] = *(const half4_t*)(p0 + h * 64 + l0 * 4);
            gv1[h] = *(const half4_t*)(p1 + h * 64 + l0 * 4);
        }
    }

    for (int base = rp; base < re; base += 8) {
        bool a0 = (base + 2 * g)     < re;
        bool a1 = (base + 2 * g + 1) < re;

        // prefetch next iteration (uniform branch: re is wave-uniform)
        half4_t gn0[6], gn1[6];
        if (base + 8 < re) {
            int i0 = base + 8 + 2 * g;
            int s0 = (i0     < re) ? sorted_src[i0]     : node;
            int s1 = (i0 + 1 < re) ? sorted_src[i0 + 1] : node;
            const _Float16* p0 = glr + (size_t)s0 * 768;
            const _Float16* p1 = glr + (size_t)s1 * 768;
            #pragma unroll
            for (int h = 0; h < 6; h++) {
                gn0[h] = *(const half4_t*)(p0 + h * 64 + l0 * 4);
                gn1[h] = *(const half4_t*)(p1 + h * 64 + l0 * 4);
            }
        } else {
            #pragma unroll
            for (int h = 0; h < 6; h++) { gn0[h] = gv0[h]; gn1[h] = gv1[h]; }
        }

        // packed-f16 logits for both edges; pack pair into one h2 for butterfly
        h2 eh[6];
        #pragma unroll
        for (int h = 0; h < 6; h++) {
            h2 t00 = (h2){gv0[h][0], gv0[h][1]} + gr_h[2 * h];
            h2 t01 = (h2){gv0[h][2], gv0[h][3]} + gr_h[2 * h + 1];
            h2 t10 = (h2){gv1[h][0], gv1[h][1]} + gr_h[2 * h];
            h2 t11 = (h2){gv1[h][2], gv1[h][3]} + gr_h[2 * h + 1];
            h2 u00 = h2max(t00, t00 * c02);
            h2 u01 = h2max(t01, t01 * c02);
            h2 u10 = h2max(t10, t10 * c02);
            h2 u11 = h2max(t11, t11 * c02);
            float d0 = FDOT2(u01, att_h[2 * h + 1], FDOT2(u00, att_h[2 * h], 0.f));
            float d1 = FDOT2(u11, att_h[2 * h + 1], FDOT2(u10, att_h[2 * h], 0.f));
            eh[h] = (h2){(_Float16)d0, (_Float16)d1};
        }
        #pragma unroll
        for (int d = 1; d < 16; d <<= 1) {
            #pragma unroll
            for (int h = 0; h < 6; h++) {
                u32 uu = __builtin_bit_cast(u32, eh[h]);
                h2 o = __builtin_bit_cast(h2, (u32)__shfl_xor((int)uu, d, 64));
                eh[h] += o;
            }
        }

        #pragma unroll
        for (int h = 0; h < 6; h++) {
            float e0 = a0 ? (float)eh[h][0] : -1e30f;
            float e1 = a1 ? (float)eh[h][1] : -1e30f;
            float mo = m[h];
            float mn = fmaxf(fmaxf(mo, e0), e1);
            float r  = exp2f(mo - mn);
            float p0 = a0 ? exp2f(e0 - mn) : 0.f;
            float p1 = a1 ? exp2f(e1 - mn) : 0.f;
            m[h] = mn;
            sden[h] = sden[h] * r + p0 + p1;
            _Float16 rh = (_Float16)r, p0h = (_Float16)p0, p1h = (_Float16)p1;
            h2 r2 = (h2){rh, rh}, p02 = (h2){p0h, p0h}, p12 = (h2){p1h, p1h};
            acc[2 * h]     = acc[2 * h]     * r2 + p02 * (h2){gv0[h][0], gv0[h][1]}
                                                 + p12 * (h2){gv1[h][0], gv1[h][1]};
            acc[2 * h + 1] = acc[2 * h + 1] * r2 + p02 * (h2){gv0[h][2], gv0[h][3]}
                                                 + p12 * (h2){gv1[h][2], gv1[h][3]};
        }
        #pragma unroll
        for (int h = 0; h < 6; h++) { gv0[h] = gn0[h]; gv1[h] = gn1[h]; }
    }

    // merge the 4 group-partial softmax states (butterfly over xor 16, 32)
    #pragma unroll
    for (int d = 16; d < 64; d <<= 1) {
        #pragma unroll
        for (int h = 0; h < 6; h++) {
            float mo = __shfl_xor(m[h], d, 64);
            float so = __shfl_xor(sden[h], d, 64);
            u32 a0u = __builtin_bit_cast(u32, acc[2 * h]);
            u32 a1u = __builtin_bit_cast(u32, acc[2 * h + 1]);
            h2 a0o = __builtin_bit_cast(h2, (u32)__shfl_xor((int)a0u, d, 64));
            h2 a1o = __builtin_bit_cast(h2, (u32)__shfl_xor((int)a1u, d, 64));
            float mn = fmaxf(m[h], mo);
            float ra = exp2f(m[h] - mn);
            float rb = exp2f(mo - mn);
            sden[h] = sden[h] * ra + so * rb;
            _Float16 rah = (_Float16)ra, rbh = (_Float16)rb;
            h2 ra2 = (h2){rah, rah}, rb2 = (h2){rbh, rbh};
            acc[2 * h]     = acc[2 * h]     * ra2 + a0o * rb2;
            acc[2 * h + 1] = acc[2 * h + 1] * ra2 + a1o * rb2;
            m[h] = mn;
        }
    }

    if (g == 0) {
        float inv[6];
        #pragma unroll
        for (int h = 0; h < 6; h++) inv[h] = 1.0f / (sden[h] + 1e-16f);
        f32x4 bv = *(const f32x4*)(bias + l0 * 4);
        f32x4 ov;
        #pragma unroll
        for (int j = 0; j < 4; j++) {
            float sum = 0.f;
            #pragma unroll
            for (int h = 0; h < 6; h++) {
                h2 a = acc[2 * h + (j >> 1)];
                sum += (float)a[j & 1] * inv[h];
            }
            float o = sum * (1.0f / 6.0f) + bv[j];
            o = (o > 0.f) ? SELU_SCALE * o
                          : SELU_SCALE * SELU_ALPHA * (__expf(o) - 1.0f);
            ov[j] = o;
        }
        *(f32x4*)(out + (size_t)node * 64 + l0 * 4) = ov;
    }
}

// ---------------- launch ----------------
extern "C" void kernel_launch(void* const* d_in, const int* in_sizes, int n_in,
                              void* d_out, int out_size, void* d_ws, size_t ws_size,
                              hipStream_t stream) {
    const float* x    = (const float*)d_in[0];
    const int*   eidx = (const int*)d_in[1];
    const float* Wl   = (const float*)d_in[2];
    const float* Wr   = (const float*)d_in[3];
    const float* att  = (const float*)d_in[4];
    const float* bias = (const float*)d_in[5];
    float* out = (float*)d_out;

    int n = in_sizes[0] / 64;        // nodes
    int E = in_sizes[1] / 2;         // edges (pre-self-loop)
    int Et = E + n;

    char* w = (char*)d_ws;
    size_t off = 0;
    auto carve = [&](size_t bytes) {
        void* p = w + off;
        off = (off + bytes + 255) & ~(size_t)255;
        return p;
    };
    _Float16* glr   = (_Float16*)carve((size_t)n * 768 * sizeof(_Float16));
    int* count      = (int*)carve((size_t)n * sizeof(int));
    int* row_ptr    = (int*)carve((size_t)(n + 1) * sizeof(int));
    int* cursor     = (int*)carve((size_t)n * sizeof(int));
    int* sorted_src = (int*)carve((size_t)Et * sizeof(int));
    int* blksum     = (int*)carve(64 * sizeof(int));
    (void)ws_size;

    int nb_n = (n + 255) / 256;
    int nb_e = (E + 255) / 256;
    int nblk = (n + 1023) / 1024;    // 49 for n=50000 (<= 64 required)

    hipMemsetAsync(count, 0, (size_t)n * sizeof(int), stream);
    hipLaunchKernelGGL(hist_kernel, dim3(nb_e), dim3(256), 0, stream, eidx, count, E);
    hipLaunchKernelGGL(scan_local_kernel, dim3(nblk), dim3(256), 0, stream,
                       count, row_ptr, blksum, n);
    hipLaunchKernelGGL(scan_blk_kernel, dim3(1), dim3(64), 0, stream,
                       blksum, row_ptr, nblk, n);
    hipLaunchKernelGGL(cursor_kernel, dim3(nb_n), dim3(256), 0, stream,
                       row_ptr, blksum, cursor, sorted_src, n);
    hipLaunchKernelGGL(scatter_kernel, dim3(nb_e), dim3(256), 0, stream,
                       eidx, cursor, sorted_src, E);
    hipLaunchKernelGGL(gemm_kernel, dim3((n + 15) / 16), dim3(256), 0, stream,
                       x, Wl, Wr, glr, n);
    hipLaunchKernelGGL(edge_kernel, dim3((n + 3) / 4), dim3(256), 0, stream,
                       glr, row_ptr, sorted_src, att, bias, out, n);
}

// Round 4
// 265.863 us; speedup vs baseline: 1.1927x; 1.1927x over previous
//
#include <hip/hip_runtime.h>
#include <hip/hip_bf16.h>
#include <hip/hip_fp16.h>

typedef _Float16 half8 __attribute__((ext_vector_type(8)));
typedef _Float16 half4_t __attribute__((ext_vector_type(4)));
typedef _Float16 h2 __attribute__((ext_vector_type(2)));
typedef float f32x4 __attribute__((ext_vector_type(4)));
typedef unsigned int u32;

#define NEG_SLOPE 0.2f
#define SELU_SCALE 1.0507009873554805f
#define SELU_ALPHA 1.6732632423543772f
#define LOG2E 1.4426950408889634f

#if __has_builtin(__builtin_amdgcn_fdot2)
#define FDOT2(a, b, c) __builtin_amdgcn_fdot2((a), (b), (c), false)
#else
static __device__ inline float FDOT2(h2 a, h2 b, float c) {
    return c + (float)a[0] * (float)b[0] + (float)a[1] * (float)b[1];
}
#endif

static __device__ inline h2 h2max(h2 a, h2 b) {
#if __has_builtin(__builtin_elementwise_max)
    return __builtin_elementwise_max(a, b);
#else
    h2 r; r[0] = a[0] > b[0] ? a[0] : b[0]; r[1] = a[1] > b[1] ? a[1] : b[1]; return r;
#endif
}

static __device__ inline h2 shfl_h2(h2 v, int d) {
    u32 u = __builtin_bit_cast(u32, v);
    return __builtin_bit_cast(h2, (u32)__shfl_xor((int)u, d, 64));
}

// ---------------- GEMM: glr[n][c] = x[n][:] @ Wcat[:][c], c in [0,768)
// Computes D[c][node] (swapped operands) so each lane holds 4 consecutive
// cols of one node row -> 8B stores.
__global__ __launch_bounds__(256) void gemm_kernel(
    const float* __restrict__ x, const float* __restrict__ Wl,
    const float* __restrict__ Wr, _Float16* __restrict__ glr, int n_nodes)
{
    __shared__ float xs[16 * 68];
    int row0 = blockIdx.x * 16;
    if (row0 >= n_nodes) return;

    {
        int t = threadIdx.x;
        int r = t >> 4, c = (t & 15) * 4;
        int row = row0 + r;
        f32x4 v = (f32x4){0.f, 0.f, 0.f, 0.f};
        if (row < n_nodes) v = *(const f32x4*)(x + (size_t)row * 64 + c);
        *(f32x4*)(xs + r * 68 + c) = v;
    }
    __syncthreads();

    int wid  = threadIdx.x >> 6;
    int lane = threadIdx.x & 63;
    int l15  = lane & 15;
    int g    = lane >> 4;
    int kb   = g * 8;

    // B-frag (K x N): node = col = l15, k = kb+j
    half8 a0, a1;
    #pragma unroll
    for (int j = 0; j < 8; j++) {
        a0[j] = (_Float16)xs[l15 * 68 + kb + j];
        a1[j] = (_Float16)xs[l15 * 68 + 32 + kb + j];
    }

    int colbase = wid * 192;
    f32x4 acc[12];
    #pragma unroll
    for (int t = 0; t < 12; t++) acc[t] = (f32x4){0.f, 0.f, 0.f, 0.f};

    #pragma unroll
    for (int t = 0; t < 12; t++) {
        int col = colbase + t * 16 + l15;   // A-frag row m = c
        const float* wcol = (col < 384) ? (Wl + col) : (Wr + (col - 384));
        half8 b0, b1;
        #pragma unroll
        for (int j = 0; j < 8; j++) {
            b0[j] = (_Float16)wcol[(size_t)(kb + j) * 384];
            b1[j] = (_Float16)wcol[(size_t)(32 + kb + j) * 384];
        }
        // D = A(=W^T) x B(=x^T):  D[c][node]
        acc[t] = __builtin_amdgcn_mfma_f32_16x16x32_f16(b0, a0, acc[t], 0, 0, 0);
        acc[t] = __builtin_amdgcn_mfma_f32_16x16x32_f16(b1, a1, acc[t], 0, 0, 0);
    }
    // D layout: col(lane&15)=node, row((lane>>4)*4+r)=c_local
    int nodeRow = row0 + l15;
    if (nodeRow < n_nodes) {
        #pragma unroll
        for (int t = 0; t < 12; t++) {
            int c0 = colbase + t * 16 + g * 4;
            half4_t hv;
            #pragma unroll
            for (int r = 0; r < 4; r++) hv[r] = (_Float16)acc[t][r];
            *(half4_t*)(glr + (size_t)nodeRow * 768 + c0) = hv;
        }
    }
}

// ---------------- CSR build ----------------
__global__ void hist_kernel(const int* __restrict__ eidx, int* count, int n_edges) {
    int i = blockIdx.x * blockDim.x + threadIdx.x;
    if (i < n_edges) atomicAdd(&count[eidx[n_edges + i]], 1);  // dst row
}

__global__ __launch_bounds__(256) void scan_local_kernel(
    const int* __restrict__ count, int* __restrict__ row_ptr,
    int* __restrict__ blksum, int n)
{
    __shared__ int ws[4];
    int blk = blockIdx.x, t = threadIdx.x;
    int base = blk * 1024 + t * 4;
    int a0 = (base + 0 < n) ? count[base + 0] + 1 : 0;
    int a1 = (base + 1 < n) ? count[base + 1] + 1 : 0;
    int a2 = (base + 2 < n) ? count[base + 2] + 1 : 0;
    int a3 = (base + 3 < n) ? count[base + 3] + 1 : 0;
    int tsum = a0 + a1 + a2 + a3;
    int lane = t & 63, wid = t >> 6;
    int s = tsum;
    #pragma unroll
    for (int d = 1; d < 64; d <<= 1) {
        int u = __shfl_up(s, d, 64);
        if (lane >= d) s += u;
    }
    if (lane == 63) ws[wid] = s;
    __syncthreads();
    int woff = 0;
    #pragma unroll
    for (int w = 0; w < 4; w++) if (w < wid) woff += ws[w];
    int excl = woff + s - tsum;
    if (base + 0 < n) row_ptr[base + 0] = excl;
    if (base + 1 < n) row_ptr[base + 1] = excl + a0;
    if (base + 2 < n) row_ptr[base + 2] = excl + a0 + a1;
    if (base + 3 < n) row_ptr[base + 3] = excl + a0 + a1 + a2;
    if (t == 255) blksum[blk] = woff + s;
}

__global__ __launch_bounds__(64) void scan_blk_kernel(
    int* __restrict__ blksum, int* __restrict__ row_ptr, int nblk, int n)
{
    int lane = threadIdx.x;
    int v = (lane < nblk) ? blksum[lane] : 0;
    int s = v;
    #pragma unroll
    for (int d = 1; d < 64; d <<= 1) {
        int u = __shfl_up(s, d, 64);
        if (lane >= d) s += u;
    }
    if (lane < nblk) blksum[lane] = s - v;
    if (lane == 63) row_ptr[n] = s;
}

__global__ void cursor_kernel(int* __restrict__ row_ptr,
                              const int* __restrict__ blksum,
                              int* __restrict__ cursor,
                              int* __restrict__ sorted_src, int n) {
    int i = blockIdx.x * blockDim.x + threadIdx.x;
    if (i < n) {
        int rp = row_ptr[i] + blksum[i >> 10];
        row_ptr[i] = rp;
        cursor[i] = rp + 1;     // slot rp reserved for self-loop
        sorted_src[rp] = i;
    }
}

__global__ void scatter_kernel(const int* __restrict__ eidx, int* cursor,
                               int* sorted_src, int n_edges) {
    int i = blockIdx.x * blockDim.x + threadIdx.x;
    if (i < n_edges) {
        int d = eidx[n_edges + i];
        int s = eidx[i];
        int pos = atomicAdd(&cursor[d], 1);
        sorted_src[pos] = s;
    }
}

// ---------------- Edge phase: one wave per dst node ----------
// Pair-octet layout: lane l0 owns 16B at byte P*256 + l0*16 of each row
// (P = head-pair 0..2). Octet o=l0>>3 selects head h=2P+o; q=l0&7 gives
// f = q*8..q*8+7. Each lane tracks only 3 heads; butterfly = 3 steps.
__global__ __launch_bounds__(256) void edge_kernel(
    const _Float16* __restrict__ glr,     // [n][768]: gl bytes 0..767? (gl 0..383 cols, gr 384..767)
    const int* __restrict__ row_ptr,
    const int* __restrict__ sorted_src,
    const float* __restrict__ att,        // [6][64]
    const float* __restrict__ bias,       // [64]
    float* __restrict__ out, int n_nodes)
{
    int wid  = threadIdx.x >> 6;
    int lane = threadIdx.x & 63;
    int node = blockIdx.x * 4 + wid;
    if (node >= n_nodes) return;
    int g   = lane >> 4;
    int l0  = lane & 15;
    int oct = l0 >> 3;
    int q   = l0 & 7;
    u32 l16 = (u32)l0 * 16u;

    const char* glr_b = (const char*)glr;
    const _Float16 c02 = (_Float16)NEG_SLOPE;

    // att (pre-scaled to log2 domain) and gr in pair-octet layout
    h2 att_h[12], gr_h[12];
    {
        u32 rbase = (u32)node * 1536u;
        #pragma unroll
        for (int P = 0; P < 3; P++) {
            int h = 2 * P + oct;
            f32x4 av0 = *(const f32x4*)(att + h * 64 + q * 8);
            f32x4 av1 = *(const f32x4*)(att + h * 64 + q * 8 + 4);
            att_h[P * 4 + 0] = (h2){(_Float16)(av0[0] * LOG2E), (_Float16)(av0[1] * LOG2E)};
            att_h[P * 4 + 1] = (h2){(_Float16)(av0[2] * LOG2E), (_Float16)(av0[3] * LOG2E)};
            att_h[P * 4 + 2] = (h2){(_Float16)(av1[0] * LOG2E), (_Float16)(av1[1] * LOG2E)};
            att_h[P * 4 + 3] = (h2){(_Float16)(av1[2] * LOG2E), (_Float16)(av1[3] * LOG2E)};
            half8 gv = *(const half8*)(glr_b + rbase + 768u + (u32)P * 256u + l16);
            gr_h[P * 4 + 0] = ((h2*)&gv)[0];
            gr_h[P * 4 + 1] = ((h2*)&gv)[1];
            gr_h[P * 4 + 2] = ((h2*)&gv)[2];
            gr_h[P * 4 + 3] = ((h2*)&gv)[3];
        }
    }

    float m[3], sden[3];
    h2 acc[12];
    #pragma unroll
    for (int P = 0; P < 3; P++) { m[P] = -1e30f; sden[P] = 0.f; }
    #pragma unroll
    for (int j = 0; j < 12; j++) acc[j] = (h2){(_Float16)0.f, (_Float16)0.f};

    int rp = row_ptr[node], re = row_ptr[node + 1];
    int reclamp = re - 1;

    auto lsrc = [&](int idx) {
        int ii = idx < reclamp ? idx : reclamp;
        return sorted_src[ii];
    };

    half8 A0, A1, A2, B0, B1, B2;
    {
        u32 o = (u32)lsrc(rp + g) * 1536u + l16;
        A0 = *(const half8*)(glr_b + o);
        A1 = *(const half8*)(glr_b + o + 256);
        A2 = *(const half8*)(glr_b + o + 512);
    }
    int sN = lsrc(rp + 4 + g);

#define PROC(X0, X1, X2, BASE)                                               \
    {                                                                        \
        bool active = ((BASE) + g) < re;                                     \
        float e[3];                                                          \
        _Pragma("unroll")                                                    \
        for (int P = 0; P < 3; P++) {                                        \
            h2 t0 = ((h2*)&X0)[0], t1 = ((h2*)&X0)[1],                       \
               t2 = ((h2*)&X0)[2], t3 = ((h2*)&X0)[3];                       \
            if (P == 1) { t0 = ((h2*)&X1)[0]; t1 = ((h2*)&X1)[1];            \
                          t2 = ((h2*)&X1)[2]; t3 = ((h2*)&X1)[3]; }          \
            if (P == 2) { t0 = ((h2*)&X2)[0]; t1 = ((h2*)&X2)[1];            \
                          t2 = ((h2*)&X2)[2]; t3 = ((h2*)&X2)[3]; }          \
            t0 = t0 + gr_h[P * 4 + 0]; t1 = t1 + gr_h[P * 4 + 1];            \
            t2 = t2 + gr_h[P * 4 + 2]; t3 = t3 + gr_h[P * 4 + 3];            \
            t0 = h2max(t0, t0 * c02); t1 = h2max(t1, t1 * c02);              \
            t2 = h2max(t2, t2 * c02); t3 = h2max(t3, t3 * c02);              \
            e[P] = FDOT2(t3, att_h[P * 4 + 3], FDOT2(t2, att_h[P * 4 + 2],   \
                   FDOT2(t1, att_h[P * 4 + 1], FDOT2(t0, att_h[P * 4 + 0],   \
                   0.f))));                                                  \
        }                                                                    \
        _Pragma("unroll")                                                    \
        for (int d = 1; d < 8; d <<= 1) {                                    \
            e[0] += __shfl_xor(e[0], d, 64);                                 \
            e[1] += __shfl_xor(e[1], d, 64);                                 \
            e[2] += __shfl_xor(e[2], d, 64);                                 \
        }                                                                    \
        if (active) {                                                        \
            _Pragma("unroll")                                                \
            for (int P = 0; P < 3; P++) {                                    \
                float mo = m[P];                                             \
                float mn = fmaxf(mo, e[P]);                                  \
                float r  = exp2f(mo - mn);                                   \
                float p  = exp2f(e[P] - mn);                                 \
                m[P] = mn;                                                   \
                sden[P] = sden[P] * r + p;                                   \
                _Float16 rh = (_Float16)r, ph = (_Float16)p;                 \
                h2 r2 = (h2){rh, rh}, p2 = (h2){ph, ph};                     \
                const h2* xv = (P == 0) ? (const h2*)&X0                     \
                             : (P == 1) ? (const h2*)&X1 : (const h2*)&X2;   \
                acc[P * 4 + 0] = acc[P * 4 + 0] * r2 + p2 * xv[0];           \
                acc[P * 4 + 1] = acc[P * 4 + 1] * r2 + p2 * xv[1];           \
                acc[P * 4 + 2] = acc[P * 4 + 2] * r2 + p2 * xv[2];           \
                acc[P * 4 + 3] = acc[P * 4 + 3] * r2 + p2 * xv[3];           \
            }                                                                \
        }                                                                    \
    }

    for (int base = rp; base < re; ) {
        {   // prefetch data for base+4 into B; src for base+8
            u32 o = (u32)sN * 1536u + l16;
            B0 = *(const half8*)(glr_b + o);
            B1 = *(const half8*)(glr_b + o + 256);
            B2 = *(const half8*)(glr_b + o + 512);
        }
        int sN2 = lsrc(base + 8 + g);
        PROC(A0, A1, A2, base);
        base += 4;
        if (base >= re) break;
        {   // prefetch data for base+4 into A; src for base+8
            u32 o = (u32)sN2 * 1536u + l16;
            A0 = *(const half8*)(glr_b + o);
            A1 = *(const half8*)(glr_b + o + 256);
            A2 = *(const half8*)(glr_b + o + 512);
        }
        sN = lsrc(base + 8 + g);
        PROC(B0, B1, B2, base);
        base += 4;
    }
#undef PROC

    // merge the 4 group-partial states (butterfly over xor 16, 32)
    #pragma unroll
    for (int d = 16; d < 64; d <<= 1) {
        #pragma unroll
        for (int P = 0; P < 3; P++) {
            float mo = __shfl_xor(m[P], d, 64);
            float so = __shfl_xor(sden[P], d, 64);
            h2 ao0 = shfl_h2(acc[P * 4 + 0], d);
            h2 ao1 = shfl_h2(acc[P * 4 + 1], d);
            h2 ao2 = shfl_h2(acc[P * 4 + 2], d);
            h2 ao3 = shfl_h2(acc[P * 4 + 3], d);
            float mn = fmaxf(m[P], mo);
            float ra = exp2f(m[P] - mn);
            float rb = exp2f(mo - mn);
            sden[P] = sden[P] * ra + so * rb;
            _Float16 rah = (_Float16)ra, rbh = (_Float16)rb;
            h2 ra2 = (h2){rah, rah}, rb2 = (h2){rbh, rbh};
            acc[P * 4 + 0] = acc[P * 4 + 0] * ra2 + ao0 * rb2;
            acc[P * 4 + 1] = acc[P * 4 + 1] * ra2 + ao1 * rb2;
            acc[P * 4 + 2] = acc[P * 4 + 2] * ra2 + ao2 * rb2;
            acc[P * 4 + 3] = acc[P * 4 + 3] * ra2 + ao3 * rb2;
            m[P] = mn;
        }
    }

    // per-lane: weight by 1/denom, sum own 3 heads, then add partner octet
    h2 iv[3];
    #pragma unroll
    for (int P = 0; P < 3; P++) {
        float inv = 1.0f / (sden[P] + 1e-16f);
        _Float16 ih = (_Float16)inv;
        iv[P] = (h2){ih, ih};
    }
    float of[8];
    #pragma unroll
    for (int j = 0; j < 4; j++) {
        h2 o = acc[0 * 4 + j] * iv[0] + acc[1 * 4 + j] * iv[1] + acc[2 * 4 + j] * iv[2];
        o = o + shfl_h2(o, 8);           // partner octet: other 3 heads
        of[2 * j]     = (float)o[0];
        of[2 * j + 1] = (float)o[1];
    }

    if (lane < 8) {                       // g==0, oct==0, q=lane
        f32x4 b0 = *(const f32x4*)(bias + q * 8);
        f32x4 b1 = *(const f32x4*)(bias + q * 8 + 4);
        f32x4 ov0, ov1;
        #pragma unroll
        for (int k = 0; k < 4; k++) {
            float v0 = of[k] * (1.0f / 6.0f) + b0[k];
            float v1 = of[k + 4] * (1.0f / 6.0f) + b1[k];
            ov0[k] = (v0 > 0.f) ? SELU_SCALE * v0
                                : SELU_SCALE * SELU_ALPHA * (__expf(v0) - 1.0f);
            ov1[k] = (v1 > 0.f) ? SELU_SCALE * v1
                                : SELU_SCALE * SELU_ALPHA * (__expf(v1) - 1.0f);
        }
        float* op = out + (size_t)node * 64 + q * 8;
        *(f32x4*)op = ov0;
        *(f32x4*)(op + 4) = ov1;
    }
}

// ---------------- launch ----------------
extern "C" void kernel_launch(void* const* d_in, const int* in_sizes, int n_in,
                              void* d_out, int out_size, void* d_ws, size_t ws_size,
                              hipStream_t stream) {
    const float* x    = (const float*)d_in[0];
    const int*   eidx = (const int*)d_in[1];
    const float* Wl   = (const float*)d_in[2];
    const float* Wr   = (const float*)d_in[3];
    const float* att  = (const float*)d_in[4];
    const float* bias = (const float*)d_in[5];
    float* out = (float*)d_out;

    int n = in_sizes[0] / 64;        // nodes
    int E = in_sizes[1] / 2;         // edges (pre-self-loop)
    int Et = E + n;

    char* w = (char*)d_ws;
    size_t off = 0;
    auto carve = [&](size_t bytes) {
        void* p = w + off;
        off = (off + bytes + 255) & ~(size_t)255;
        return p;
    };
    _Float16* glr   = (_Float16*)carve((size_t)n * 768 * sizeof(_Float16));
    int* count      = (int*)carve((size_t)n * sizeof(int));
    int* row_ptr    = (int*)carve((size_t)(n + 1) * sizeof(int));
    int* cursor     = (int*)carve((size_t)n * sizeof(int));
    int* sorted_src = (int*)carve((size_t)Et * sizeof(int));
    int* blksum     = (int*)carve(64 * sizeof(int));
    (void)ws_size;

    int nb_n = (n + 255) / 256;
    int nb_e = (E + 255) / 256;
    int nblk = (n + 1023) / 1024;    // 49 for n=50000 (<= 64 required)

    hipMemsetAsync(count, 0, (size_t)n * sizeof(int), stream);
    hipLaunchKernelGGL(hist_kernel, dim3(nb_e), dim3(256), 0, stream, eidx, count, E);
    hipLaunchKernelGGL(scan_local_kernel, dim3(nblk), dim3(256), 0, stream,
                       count, row_ptr, blksum, n);
    hipLaunchKernelGGL(scan_blk_kernel, dim3(1), dim3(64), 0, stream,
                       blksum, row_ptr, nblk, n);
    hipLaunchKernelGGL(cursor_kernel, dim3(nb_n), dim3(256), 0, stream,
                       row_ptr, blksum, cursor, sorted_src, n);
    hipLaunchKernelGGL(scatter_kernel, dim3(nb_e), dim3(256), 0, stream,
                       eidx, cursor, sorted_src, E);
    hipLaunchKernelGGL(gemm_kernel, dim3((n + 15) / 16), dim3(256), 0, stream,
                       x, Wl, Wr, glr, n);
    hipLaunchKernelGGL(edge_kernel, dim3((n + 3) / 4), dim3(256), 0, stream,
                       glr, row_ptr, sorted_src, att, bias, out, n);
}

// Round 5
// 251.016 us; speedup vs baseline: 1.2632x; 1.0591x over previous
//
#include <hip/hip_runtime.h>
#include <hip/hip_bf16.h>
#include <hip/hip_fp16.h>

typedef _Float16 half8 __attribute__((ext_vector_type(8)));
typedef _Float16 half4_t __attribute__((ext_vector_type(4)));
typedef _Float16 h2 __attribute__((ext_vector_type(2)));
typedef float f32x4 __attribute__((ext_vector_type(4)));
typedef unsigned int u32;

#define NEG_SLOPE 0.2f
#define SELU_SCALE 1.0507009873554805f
#define SELU_ALPHA 1.6732632423543772f
#define LOG2E 1.4426950408889634f

#if __has_builtin(__builtin_amdgcn_fdot2)
#define FDOT2(a, b, c) __builtin_amdgcn_fdot2((a), (b), (c), false)
#else
static __device__ inline float FDOT2(h2 a, h2 b, float c) {
    return c + (float)a[0] * (float)b[0] + (float)a[1] * (float)b[1];
}
#endif

static __device__ inline h2 h2max(h2 a, h2 b) {
#if __has_builtin(__builtin_elementwise_max)
    return __builtin_elementwise_max(a, b);
#else
    h2 r; r[0] = a[0] > b[0] ? a[0] : b[0]; r[1] = a[1] > b[1] ? a[1] : b[1]; return r;
#endif
}

static __device__ inline h2 shfl_h2(h2 v, int d) {
    u32 u = __builtin_bit_cast(u32, v);
    return __builtin_bit_cast(h2, (u32)__shfl_xor((int)u, d, 64));
}

// raw v_exp_f32: D = 2^S0 (flush-to-zero for huge negatives is fine here)
static __device__ inline float fexp2(float x) {
    float r;
    asm("v_exp_f32 %0, %1" : "=v"(r) : "v"(x));
    return r;
}

static __device__ inline h2 pk2(float a) {
#if __has_builtin(__builtin_amdgcn_cvt_pkrtz)
    return __builtin_bit_cast(h2, __builtin_amdgcn_cvt_pkrtz(a, a));
#else
    _Float16 h = (_Float16)a; return (h2){h, h};
#endif
}

// ---------------- GEMM: glr[n][c] = x[n][:] @ Wcat[:][c], c in [0,768)
// 64 rows per block; W fragments loaded once per wave, reused for 4 row-tiles.
// Swapped MFMA (D[c][node]) so each lane stores 4 consecutive cols -> 8B stores.
__global__ __launch_bounds__(256) void gemm_kernel(
    const float* __restrict__ x, const float* __restrict__ Wl,
    const float* __restrict__ Wr, _Float16* __restrict__ glr, int n_nodes)
{
    __shared__ float xs[64 * 68];
    int row0 = blockIdx.x * 64;
    if (row0 >= n_nodes) return;

    {
        int t = threadIdx.x;
        #pragma unroll
        for (int i = 0; i < 4; i++) {
            int idx = t + i * 256;           // 1024 float4 total
            int r = idx >> 4, c = (idx & 15) * 4;
            int row = row0 + r;
            f32x4 v = (f32x4){0.f, 0.f, 0.f, 0.f};
            if (row < n_nodes) v = *(const f32x4*)(x + (size_t)row * 64 + c);
            *(f32x4*)(xs + r * 68 + c) = v;
        }
    }
    __syncthreads();

    int wid  = threadIdx.x >> 6;
    int lane = threadIdx.x & 63;
    int l15  = lane & 15;
    int g    = lane >> 4;
    int kb   = g * 8;
    int colbase = wid * 192;

    // W fragments (A operand), register-resident across the 4 row-tiles
    half8 bw0[12], bw1[12];
    #pragma unroll
    for (int t = 0; t < 12; t++) {
        int col = colbase + t * 16 + l15;
        const float* wcol = (col < 384) ? (Wl + col) : (Wr + (col - 384));
        #pragma unroll
        for (int j = 0; j < 8; j++) {
            bw0[t][j] = (_Float16)wcol[(size_t)(kb + j) * 384];
            bw1[t][j] = (_Float16)wcol[(size_t)(32 + kb + j) * 384];
        }
    }

    #pragma unroll
    for (int rt = 0; rt < 4; rt++) {
        int r0 = rt * 16;
        half8 a0, a1;
        #pragma unroll
        for (int j = 0; j < 8; j++) {
            a0[j] = (_Float16)xs[(r0 + l15) * 68 + kb + j];
            a1[j] = (_Float16)xs[(r0 + l15) * 68 + 32 + kb + j];
        }
        int nodeRow = row0 + r0 + l15;
        #pragma unroll
        for (int t = 0; t < 12; t++) {
            f32x4 acc = (f32x4){0.f, 0.f, 0.f, 0.f};
            acc = __builtin_amdgcn_mfma_f32_16x16x32_f16(bw0[t], a0, acc, 0, 0, 0);
            acc = __builtin_amdgcn_mfma_f32_16x16x32_f16(bw1[t], a1, acc, 0, 0, 0);
            if (nodeRow < n_nodes) {
                int c0 = colbase + t * 16 + g * 4;
                half4_t hv;
                #pragma unroll
                for (int r = 0; r < 4; r++) hv[r] = (_Float16)acc[r];
                *(half4_t*)(glr + (size_t)nodeRow * 768 + c0) = hv;
            }
        }
    }
}

// ---------------- CSR build ----------------
__global__ void hist_kernel(const int* __restrict__ eidx, int* count, int n_edges) {
    int i = blockIdx.x * blockDim.x + threadIdx.x;
    if (i < n_edges) atomicAdd(&count[eidx[n_edges + i]], 1);  // dst row
}

__global__ __launch_bounds__(256) void scan_local_kernel(
    const int* __restrict__ count, int* __restrict__ row_ptr,
    int* __restrict__ blksum, int n)
{
    __shared__ int ws[4];
    int blk = blockIdx.x, t = threadIdx.x;
    int base = blk * 1024 + t * 4;
    int a0 = (base + 0 < n) ? count[base + 0] + 1 : 0;
    int a1 = (base + 1 < n) ? count[base + 1] + 1 : 0;
    int a2 = (base + 2 < n) ? count[base + 2] + 1 : 0;
    int a3 = (base + 3 < n) ? count[base + 3] + 1 : 0;
    int tsum = a0 + a1 + a2 + a3;
    int lane = t & 63, wid = t >> 6;
    int s = tsum;
    #pragma unroll
    for (int d = 1; d < 64; d <<= 1) {
        int u = __shfl_up(s, d, 64);
        if (lane >= d) s += u;
    }
    if (lane == 63) ws[wid] = s;
    __syncthreads();
    int woff = 0;
    #pragma unroll
    for (int w = 0; w < 4; w++) if (w < wid) woff += ws[w];
    int excl = woff + s - tsum;
    if (base + 0 < n) row_ptr[base + 0] = excl;
    if (base + 1 < n) row_ptr[base + 1] = excl + a0;
    if (base + 2 < n) row_ptr[base + 2] = excl + a0 + a1;
    if (base + 3 < n) row_ptr[base + 3] = excl + a0 + a1 + a2;
    if (t == 255) blksum[blk] = woff + s;
}

__global__ __launch_bounds__(64) void scan_blk_kernel(
    int* __restrict__ blksum, int* __restrict__ row_ptr, int nblk, int n)
{
    int lane = threadIdx.x;
    int v = (lane < nblk) ? blksum[lane] : 0;
    int s = v;
    #pragma unroll
    for (int d = 1; d < 64; d <<= 1) {
        int u = __shfl_up(s, d, 64);
        if (lane >= d) s += u;
    }
    if (lane < nblk) blksum[lane] = s - v;
    if (lane == 63) row_ptr[n] = s;
}

__global__ void cursor_kernel(int* __restrict__ row_ptr,
                              const int* __restrict__ blksum,
                              int* __restrict__ cursor,
                              int* __restrict__ sorted_src, int n) {
    int i = blockIdx.x * blockDim.x + threadIdx.x;
    if (i < n) {
        int rp = row_ptr[i] + blksum[i >> 10];
        row_ptr[i] = rp;
        cursor[i] = rp + 1;     // slot rp reserved for self-loop
        sorted_src[rp] = i;
    }
}

__global__ void scatter_kernel(const int* __restrict__ eidx, int* cursor,
                               int* sorted_src, int n_edges) {
    int i = blockIdx.x * blockDim.x + threadIdx.x;
    if (i < n_edges) {
        int d = eidx[n_edges + i];
        int s = eidx[i];
        int pos = atomicAdd(&cursor[d], 1);
        sorted_src[pos] = s;
    }
}

// ---------------- Edge phase: one wave per dst node ----------
// Pair-octet layout: lane l0 owns 16B at byte P*256 + l0*16 (P = head-pair).
// oct=l0>>3 selects head 2P+oct; q=l0&7 gives f=q*8..q*8+7. 3 heads/lane.
// Software pipeline: gl data loads issued 2 PROC-bodies ahead (A/B/C rotation).
__global__ __launch_bounds__(256) void edge_kernel(
    const _Float16* __restrict__ glr,
    const int* __restrict__ row_ptr,
    const int* __restrict__ sorted_src,
    const float* __restrict__ att,        // [6][64]
    const float* __restrict__ bias,       // [64]
    float* __restrict__ out, int n_nodes)
{
    int wid  = threadIdx.x >> 6;
    int lane = threadIdx.x & 63;
    int node = blockIdx.x * 4 + wid;
    if (node >= n_nodes) return;
    int g   = lane >> 4;
    int l0  = lane & 15;
    int oct = l0 >> 3;
    int q   = l0 & 7;
    u32 l16 = (u32)l0 * 16u;

    const char* glr_b = (const char*)glr;
    const _Float16 c02 = (_Float16)NEG_SLOPE;

    h2 att_h[12], gr_h[12];
    {
        u32 rbase = (u32)node * 1536u;
        #pragma unroll
        for (int P = 0; P < 3; P++) {
            int h = 2 * P + oct;
            f32x4 av0 = *(const f32x4*)(att + h * 64 + q * 8);
            f32x4 av1 = *(const f32x4*)(att + h * 64 + q * 8 + 4);
            att_h[P * 4 + 0] = (h2){(_Float16)(av0[0] * LOG2E), (_Float16)(av0[1] * LOG2E)};
            att_h[P * 4 + 1] = (h2){(_Float16)(av0[2] * LOG2E), (_Float16)(av0[3] * LOG2E)};
            att_h[P * 4 + 2] = (h2){(_Float16)(av1[0] * LOG2E), (_Float16)(av1[1] * LOG2E)};
            att_h[P * 4 + 3] = (h2){(_Float16)(av1[2] * LOG2E), (_Float16)(av1[3] * LOG2E)};
            half8 gv = *(const half8*)(glr_b + rbase + 768u + (u32)P * 256u + l16);
            gr_h[P * 4 + 0] = ((h2*)&gv)[0];
            gr_h[P * 4 + 1] = ((h2*)&gv)[1];
            gr_h[P * 4 + 2] = ((h2*)&gv)[2];
            gr_h[P * 4 + 3] = ((h2*)&gv)[3];
        }
    }

    float m[3], sden[3];
    h2 acc[12];
    #pragma unroll
    for (int P = 0; P < 3; P++) { m[P] = -1e30f; sden[P] = 0.f; }
    #pragma unroll
    for (int j = 0; j < 12; j++) acc[j] = (h2){(_Float16)0.f, (_Float16)0.f};

    int rp = row_ptr[node], re = row_ptr[node + 1];
    int reclamp = re - 1;

    auto lsrc = [&](int idx) {
        int ii = idx < reclamp ? idx : reclamp;
        return sorted_src[ii];
    };

    half8 A0, A1, A2, B0, B1, B2, C0, C1, C2;

#define LOADX(X0, X1, X2, S)                                                 \
    {                                                                        \
        u32 o = (u32)(S) * 1536u + l16;                                      \
        X0 = *(const half8*)(glr_b + o);                                     \
        X1 = *(const half8*)(glr_b + o + 256);                               \
        X2 = *(const half8*)(glr_b + o + 512);                               \
    }

#define PROC(X0, X1, X2, BASE)                                               \
    {                                                                        \
        bool active = ((BASE) + g) < re;                                     \
        float e[3];                                                          \
        _Pragma("unroll")                                                    \
        for (int P = 0; P < 3; P++) {                                        \
            h2 t0 = ((h2*)&X0)[0], t1 = ((h2*)&X0)[1],                       \
               t2 = ((h2*)&X0)[2], t3 = ((h2*)&X0)[3];                       \
            if (P == 1) { t0 = ((h2*)&X1)[0]; t1 = ((h2*)&X1)[1];            \
                          t2 = ((h2*)&X1)[2]; t3 = ((h2*)&X1)[3]; }          \
            if (P == 2) { t0 = ((h2*)&X2)[0]; t1 = ((h2*)&X2)[1];            \
                          t2 = ((h2*)&X2)[2]; t3 = ((h2*)&X2)[3]; }          \
            t0 = t0 + gr_h[P * 4 + 0]; t1 = t1 + gr_h[P * 4 + 1];            \
            t2 = t2 + gr_h[P * 4 + 2]; t3 = t3 + gr_h[P * 4 + 3];            \
            t0 = h2max(t0, t0 * c02); t1 = h2max(t1, t1 * c02);              \
            t2 = h2max(t2, t2 * c02); t3 = h2max(t3, t3 * c02);              \
            e[P] = FDOT2(t3, att_h[P * 4 + 3], FDOT2(t2, att_h[P * 4 + 2],   \
                   FDOT2(t1, att_h[P * 4 + 1], FDOT2(t0, att_h[P * 4 + 0],   \
                   0.f))));                                                  \
        }                                                                    \
        _Pragma("unroll")                                                    \
        for (int d = 1; d < 8; d <<= 1) {                                    \
            e[0] += __shfl_xor(e[0], d, 64);                                 \
            e[1] += __shfl_xor(e[1], d, 64);                                 \
            e[2] += __shfl_xor(e[2], d, 64);                                 \
        }                                                                    \
        if (active) {                                                        \
            _Pragma("unroll")                                                \
            for (int P = 0; P < 3; P++) {                                    \
                float mo = m[P];                                             \
                float mn = fmaxf(mo, e[P]);                                  \
                float r  = fexp2(mo - mn);                                   \
                float p  = fexp2(e[P] - mn);                                 \
                m[P] = mn;                                                   \
                sden[P] = sden[P] * r + p;                                   \
                h2 r2 = pk2(r), p2 = pk2(p);                                 \
                const h2* xv = (P == 0) ? (const h2*)&X0                     \
                             : (P == 1) ? (const h2*)&X1 : (const h2*)&X2;   \
                acc[P * 4 + 0] = acc[P * 4 + 0] * r2 + p2 * xv[0];           \
                acc[P * 4 + 1] = acc[P * 4 + 1] * r2 + p2 * xv[1];           \
                acc[P * 4 + 2] = acc[P * 4 + 2] * r2 + p2 * xv[2];           \
                acc[P * 4 + 3] = acc[P * 4 + 3] * r2 + p2 * xv[3];           \
            }                                                                \
        }                                                                    \
    }

    {
        int s1 = lsrc(rp + 4 + g);
        int s2 = lsrc(rp + 8 + g);
        LOADX(A0, A1, A2, lsrc(rp + g));
        LOADX(B0, B1, B2, s1);
        int base = rp;
        for (;;) {
            // A=data(base), B=data(base+4); s2=src(base+8)
            LOADX(C0, C1, C2, s2);
            s2 = lsrc(base + 12 + g);
            PROC(A0, A1, A2, base);
            base += 4; if (base >= re) break;
            LOADX(A0, A1, A2, s2);
            s2 = lsrc(base + 12 + g);
            PROC(B0, B1, B2, base);
            base += 4; if (base >= re) break;
            LOADX(B0, B1, B2, s2);
            s2 = lsrc(base + 12 + g);
            PROC(C0, C1, C2, base);
            base += 4; if (base >= re) break;
        }
    }
#undef PROC
#undef LOADX

    // merge the 4 group-partial states (butterfly over xor 16, 32)
    #pragma unroll
    for (int d = 16; d < 64; d <<= 1) {
        #pragma unroll
        for (int P = 0; P < 3; P++) {
            float mo = __shfl_xor(m[P], d, 64);
            float so = __shfl_xor(sden[P], d, 64);
            h2 ao0 = shfl_h2(acc[P * 4 + 0], d);
            h2 ao1 = shfl_h2(acc[P * 4 + 1], d);
            h2 ao2 = shfl_h2(acc[P * 4 + 2], d);
            h2 ao3 = shfl_h2(acc[P * 4 + 3], d);
            float mn = fmaxf(m[P], mo);
            float ra = exp2f(m[P] - mn);
            float rb = exp2f(mo - mn);
            sden[P] = sden[P] * ra + so * rb;
            h2 ra2 = pk2(ra), rb2 = pk2(rb);
            acc[P * 4 + 0] = acc[P * 4 + 0] * ra2 + ao0 * rb2;
            acc[P * 4 + 1] = acc[P * 4 + 1] * ra2 + ao1 * rb2;
            acc[P * 4 + 2] = acc[P * 4 + 2] * ra2 + ao2 * rb2;
            acc[P * 4 + 3] = acc[P * 4 + 3] * ra2 + ao3 * rb2;
            m[P] = mn;
        }
    }

    h2 iv[3];
    #pragma unroll
    for (int P = 0; P < 3; P++) {
        float inv = 1.0f / (sden[P] + 1e-16f);
        _Float16 ih = (_Float16)inv;
        iv[P] = (h2){ih, ih};
    }
    float of[8];
    #pragma unroll
    for (int j = 0; j < 4; j++) {
        h2 o = acc[0 * 4 + j] * iv[0] + acc[1 * 4 + j] * iv[1] + acc[2 * 4 + j] * iv[2];
        o = o + shfl_h2(o, 8);           // partner octet: other 3 heads
        of[2 * j]     = (float)o[0];
        of[2 * j + 1] = (float)o[1];
    }

    if (lane < 8) {                       // g==0, oct==0, q=lane
        f32x4 b0 = *(const f32x4*)(bias + q * 8);
        f32x4 b1 = *(const f32x4*)(bias + q * 8 + 4);
        f32x4 ov0, ov1;
        #pragma unroll
        for (int k = 0; k < 4; k++) {
            float v0 = of[k] * (1.0f / 6.0f) + b0[k];
            float v1 = of[k + 4] * (1.0f / 6.0f) + b1[k];
            ov0[k] = (v0 > 0.f) ? SELU_SCALE * v0
                                : SELU_SCALE * SELU_ALPHA * (__expf(v0) - 1.0f);
            ov1[k] = (v1 > 0.f) ? SELU_SCALE * v1
                                : SELU_SCALE * SELU_ALPHA * (__expf(v1) - 1.0f);
        }
        float* op = out + (size_t)node * 64 + q * 8;
        *(f32x4*)op = ov0;
        *(f32x4*)(op + 4) = ov1;
    }
}

// ---------------- launch ----------------
extern "C" void kernel_launch(void* const* d_in, const int* in_sizes, int n_in,
                              void* d_out, int out_size, void* d_ws, size_t ws_size,
                              hipStream_t stream) {
    const float* x    = (const float*)d_in[0];
    const int*   eidx = (const int*)d_in[1];
    const float* Wl   = (const float*)d_in[2];
    const float* Wr   = (const float*)d_in[3];
    const float* att  = (const float*)d_in[4];
    const float* bias = (const float*)d_in[5];
    float* out = (float*)d_out;

    int n = in_sizes[0] / 64;        // nodes
    int E = in_sizes[1] / 2;         // edges (pre-self-loop)
    int Et = E + n;

    char* w = (char*)d_ws;
    size_t off = 0;
    auto carve = [&](size_t bytes) {
        void* p = w + off;
        off = (off + bytes + 255) & ~(size_t)255;
        return p;
    };
    _Float16* glr   = (_Float16*)carve((size_t)n * 768 * sizeof(_Float16));
    int* count      = (int*)carve((size_t)n * sizeof(int));
    int* row_ptr    = (int*)carve((size_t)(n + 1) * sizeof(int));
    int* cursor     = (int*)carve((size_t)n * sizeof(int));
    int* sorted_src = (int*)carve((size_t)Et * sizeof(int));
    int* blksum     = (int*)carve(64 * sizeof(int));
    (void)ws_size;

    int nb_n = (n + 255) / 256;
    int nb_e = (E + 255) / 256;
    int nblk = (n + 1023) / 1024;    // 49 for n=50000 (<= 64 required)

    hipMemsetAsync(count, 0, (size_t)n * sizeof(int), stream);
    hipLaunchKernelGGL(hist_kernel, dim3(nb_e), dim3(256), 0, stream, eidx, count, E);
    hipLaunchKernelGGL(scan_local_kernel, dim3(nblk), dim3(256), 0, stream,
                       count, row_ptr, blksum, n);
    hipLaunchKernelGGL(scan_blk_kernel, dim3(1), dim3(64), 0, stream,
                       blksum, row_ptr, nblk, n);
    hipLaunchKernelGGL(cursor_kernel, dim3(nb_n), dim3(256), 0, stream,
                       row_ptr, blksum, cursor, sorted_src, n);
    hipLaunchKernelGGL(scatter_kernel, dim3(nb_e), dim3(256), 0, stream,
                       eidx, cursor, sorted_src, E);
    hipLaunchKernelGGL(gemm_kernel, dim3((n + 63) / 64), dim3(256), 0, stream,
                       x, Wl, Wr, glr, n);
    hipLaunchKernelGGL(edge_kernel, dim3((n + 3) / 4), dim3(256), 0, stream,
                       glr, row_ptr, sorted_src, att, bias, out, n);
}

// Round 6
// 244.619 us; speedup vs baseline: 1.2963x; 1.0262x over previous
//
#include <hip/hip_runtime.h>
#include <hip/hip_bf16.h>
#include <hip/hip_fp16.h>

typedef _Float16 half8 __attribute__((ext_vector_type(8)));
typedef _Float16 half4_t __attribute__((ext_vector_type(4)));
typedef _Float16 h2 __attribute__((ext_vector_type(2)));
typedef float f32x4 __attribute__((ext_vector_type(4)));
typedef unsigned int u32;

#define NEG_SLOPE 0.2f
#define SELU_SCALE 1.0507009873554805f
#define SELU_ALPHA 1.6732632423543772f
#define LOG2E 1.4426950408889634f

#if __has_builtin(__builtin_amdgcn_fdot2)
#define FDOT2(a, b, c) __builtin_amdgcn_fdot2((a), (b), (c), false)
#else
static __device__ inline float FDOT2(h2 a, h2 b, float c) {
    return c + (float)a[0] * (float)b[0] + (float)a[1] * (float)b[1];
}
#endif

static __device__ inline h2 h2max(h2 a, h2 b) {
#if __has_builtin(__builtin_elementwise_max)
    return __builtin_elementwise_max(a, b);
#else
    h2 r; r[0] = a[0] > b[0] ? a[0] : b[0]; r[1] = a[1] > b[1] ? a[1] : b[1]; return r;
#endif
}

static __device__ inline h2 shfl_h2(h2 v, int d) {
    u32 u = __builtin_bit_cast(u32, v);
    return __builtin_bit_cast(h2, (u32)__shfl_xor((int)u, d, 64));
}

// raw v_exp_f32: D = 2^S0
static __device__ inline float fexp2(float x) {
    float r;
    asm("v_exp_f32 %0, %1" : "=v"(r) : "v"(x));
    return r;
}

static __device__ inline h2 pk2(float a) {
#if __has_builtin(__builtin_amdgcn_cvt_pkrtz)
    return __builtin_bit_cast(h2, __builtin_amdgcn_cvt_pkrtz(a, a));
#else
    _Float16 h = (_Float16)a; return (h2){h, h};
#endif
}

// ---------------- GEMM: glr[n][c] = x[n][:] @ Wcat[:][c], c in [0,768)
// 64 rows per block; W fragments register-resident across 4 row-tiles.
// Swapped MFMA (D[c][node]) so each lane stores 4 consecutive cols -> 8B stores.
__global__ __launch_bounds__(256) void gemm_kernel(
    const float* __restrict__ x, const float* __restrict__ Wl,
    const float* __restrict__ Wr, _Float16* __restrict__ glr, int n_nodes)
{
    __shared__ float xs[64 * 68];
    int row0 = blockIdx.x * 64;
    if (row0 >= n_nodes) return;

    {
        int t = threadIdx.x;
        #pragma unroll
        for (int i = 0; i < 4; i++) {
            int idx = t + i * 256;
            int r = idx >> 4, c = (idx & 15) * 4;
            int row = row0 + r;
            f32x4 v = (f32x4){0.f, 0.f, 0.f, 0.f};
            if (row < n_nodes) v = *(const f32x4*)(x + (size_t)row * 64 + c);
            *(f32x4*)(xs + r * 68 + c) = v;
        }
    }
    __syncthreads();

    int wid  = threadIdx.x >> 6;
    int lane = threadIdx.x & 63;
    int l15  = lane & 15;
    int g    = lane >> 4;
    int kb   = g * 8;
    int colbase = wid * 192;

    half8 bw0[12], bw1[12];
    #pragma unroll
    for (int t = 0; t < 12; t++) {
        int col = colbase + t * 16 + l15;
        const float* wcol = (col < 384) ? (Wl + col) : (Wr + (col - 384));
        #pragma unroll
        for (int j = 0; j < 8; j++) {
            bw0[t][j] = (_Float16)wcol[(size_t)(kb + j) * 384];
            bw1[t][j] = (_Float16)wcol[(size_t)(32 + kb + j) * 384];
        }
    }

    #pragma unroll
    for (int rt = 0; rt < 4; rt++) {
        int r0 = rt * 16;
        half8 a0, a1;
        #pragma unroll
        for (int j = 0; j < 8; j++) {
            a0[j] = (_Float16)xs[(r0 + l15) * 68 + kb + j];
            a1[j] = (_Float16)xs[(r0 + l15) * 68 + 32 + kb + j];
        }
        int nodeRow = row0 + r0 + l15;
        #pragma unroll
        for (int t = 0; t < 12; t++) {
            f32x4 acc = (f32x4){0.f, 0.f, 0.f, 0.f};
            acc = __builtin_amdgcn_mfma_f32_16x16x32_f16(bw0[t], a0, acc, 0, 0, 0);
            acc = __builtin_amdgcn_mfma_f32_16x16x32_f16(bw1[t], a1, acc, 0, 0, 0);
            if (nodeRow < n_nodes) {
                int c0 = colbase + t * 16 + g * 4;
                half4_t hv;
                #pragma unroll
                for (int r = 0; r < 4; r++) hv[r] = (_Float16)acc[r];
                *(half4_t*)(glr + (size_t)nodeRow * 768 + c0) = hv;
            }
        }
    }
}

// ---------------- CSR build ----------------
__global__ void hist_kernel(const int* __restrict__ eidx, int* count, int n_edges) {
    int i = blockIdx.x * blockDim.x + threadIdx.x;
    if (i < n_edges) atomicAdd(&count[eidx[n_edges + i]], 1);  // dst row
}

__global__ __launch_bounds__(256) void scan_local_kernel(
    const int* __restrict__ count, int* __restrict__ row_ptr,
    int* __restrict__ blksum, int n)
{
    __shared__ int ws[4];
    int blk = blockIdx.x, t = threadIdx.x;
    int base = blk * 1024 + t * 4;
    int a0 = (base + 0 < n) ? count[base + 0] + 1 : 0;
    int a1 = (base + 1 < n) ? count[base + 1] + 1 : 0;
    int a2 = (base + 2 < n) ? count[base + 2] + 1 : 0;
    int a3 = (base + 3 < n) ? count[base + 3] + 1 : 0;
    int tsum = a0 + a1 + a2 + a3;
    int lane = t & 63, wid = t >> 6;
    int s = tsum;
    #pragma unroll
    for (int d = 1; d < 64; d <<= 1) {
        int u = __shfl_up(s, d, 64);
        if (lane >= d) s += u;
    }
    if (lane == 63) ws[wid] = s;
    __syncthreads();
    int woff = 0;
    #pragma unroll
    for (int w = 0; w < 4; w++) if (w < wid) woff += ws[w];
    int excl = woff + s - tsum;
    if (base + 0 < n) row_ptr[base + 0] = excl;
    if (base + 1 < n) row_ptr[base + 1] = excl + a0;
    if (base + 2 < n) row_ptr[base + 2] = excl + a0 + a1;
    if (base + 3 < n) row_ptr[base + 3] = excl + a0 + a1 + a2;
    if (t == 255) blksum[blk] = woff + s;
}

__global__ __launch_bounds__(64) void scan_blk_kernel(
    int* __restrict__ blksum, int* __restrict__ row_ptr, int nblk, int n)
{
    int lane = threadIdx.x;
    int v = (lane < nblk) ? blksum[lane] : 0;
    int s = v;
    #pragma unroll
    for (int d = 1; d < 64; d <<= 1) {
        int u = __shfl_up(s, d, 64);
        if (lane >= d) s += u;
    }
    if (lane < nblk) blksum[lane] = s - v;
    if (lane == 63) row_ptr[n] = s;
}

__global__ void cursor_kernel(int* __restrict__ row_ptr,
                              const int* __restrict__ blksum,
                              int* __restrict__ cursor,
                              int* __restrict__ sorted_src, int n) {
    int i = blockIdx.x * blockDim.x + threadIdx.x;
    if (i < n) {
        int rp = row_ptr[i] + blksum[i >> 10];
        row_ptr[i] = rp;
        cursor[i] = rp + 1;     // slot rp reserved for self-loop
        sorted_src[rp] = i;
    }
}

__global__ void scatter_kernel(const int* __restrict__ eidx, int* cursor,
                               int* sorted_src, int n_edges) {
    int i = blockIdx.x * blockDim.x + threadIdx.x;
    if (i < n_edges) {
        int d = eidx[n_edges + i];
        int s = eidx[i];
        int pos = atomicAdd(&cursor[d], 1);
        sorted_src[pos] = s;
    }
}

// ---------------- Edge phase: persistent waves, one node per wave at a time --
// Pair-octet layout: lane l0 owns 16B at byte P*256 + l0*16 (P = head-pair).
// oct=l0>>3 selects head 2P+oct; q=l0&7 gives f=q*8..q*8+7. 3 heads/lane.
// Each wave independently grid-strides over nodes; att hoisted per wave.
__global__ __launch_bounds__(256) void edge_kernel(
    const _Float16* __restrict__ glr,
    const int* __restrict__ row_ptr,
    const int* __restrict__ sorted_src,
    const float* __restrict__ att,        // [6][64]
    const float* __restrict__ bias,       // [64]
    float* __restrict__ out, int n_nodes)
{
    int wid  = threadIdx.x >> 6;
    int lane = threadIdx.x & 63;
    int gwid = blockIdx.x * 4 + wid;           // global wave id
    int GW   = gridDim.x * 4;                  // total waves
    int g   = lane >> 4;
    int l0  = lane & 15;
    int oct = l0 >> 3;
    int q   = l0 & 7;
    u32 l16 = (u32)l0 * 16u;

    const char* glr_b = (const char*)glr;
    const _Float16 c02 = (_Float16)NEG_SLOPE;

    // att in log2 domain, hoisted out of the node loop
    h2 att_h[12];
    #pragma unroll
    for (int P = 0; P < 3; P++) {
        int h = 2 * P + oct;
        f32x4 av0 = *(const f32x4*)(att + h * 64 + q * 8);
        f32x4 av1 = *(const f32x4*)(att + h * 64 + q * 8 + 4);
        att_h[P * 4 + 0] = (h2){(_Float16)(av0[0] * LOG2E), (_Float16)(av0[1] * LOG2E)};
        att_h[P * 4 + 1] = (h2){(_Float16)(av0[2] * LOG2E), (_Float16)(av0[3] * LOG2E)};
        att_h[P * 4 + 2] = (h2){(_Float16)(av1[0] * LOG2E), (_Float16)(av1[1] * LOG2E)};
        att_h[P * 4 + 3] = (h2){(_Float16)(av1[2] * LOG2E), (_Float16)(av1[3] * LOG2E)};
    }

    for (int node = gwid; node < n_nodes; node += GW) {
        h2 gr_h[12];
        {
            u32 rbase = (u32)node * 1536u + 768u;
            #pragma unroll
            for (int P = 0; P < 3; P++) {
                half8 gv = *(const half8*)(glr_b + rbase + (u32)P * 256u + l16);
                gr_h[P * 4 + 0] = ((h2*)&gv)[0];
                gr_h[P * 4 + 1] = ((h2*)&gv)[1];
                gr_h[P * 4 + 2] = ((h2*)&gv)[2];
                gr_h[P * 4 + 3] = ((h2*)&gv)[3];
            }
        }

        float m[3], sden[3];
        h2 acc[12];
        #pragma unroll
        for (int P = 0; P < 3; P++) { m[P] = -1e30f; sden[P] = 0.f; }
        #pragma unroll
        for (int j = 0; j < 12; j++) acc[j] = (h2){(_Float16)0.f, (_Float16)0.f};

        int rp = row_ptr[node], re = row_ptr[node + 1];
        int reclamp = re - 1;

        auto lsrc = [&](int idx) {
            int ii = idx < reclamp ? idx : reclamp;
            return sorted_src[ii];
        };

        half8 A0, A1, A2, B0, B1, B2;

#define LOADX(X0, X1, X2, S)                                                 \
        {                                                                    \
            u32 o = (u32)(S) * 1536u + l16;                                  \
            X0 = *(const half8*)(glr_b + o);                                 \
            X1 = *(const half8*)(glr_b + o + 256);                           \
            X2 = *(const half8*)(glr_b + o + 512);                           \
        }

#define PROC(X0, X1, X2, BASE)                                               \
        {                                                                    \
            bool active = ((BASE) + g) < re;                                 \
            float e[3];                                                      \
            _Pragma("unroll")                                                \
            for (int P = 0; P < 3; P++) {                                    \
                h2 t0 = ((h2*)&X0)[0], t1 = ((h2*)&X0)[1],                   \
                   t2 = ((h2*)&X0)[2], t3 = ((h2*)&X0)[3];                   \
                if (P == 1) { t0 = ((h2*)&X1)[0]; t1 = ((h2*)&X1)[1];        \
                              t2 = ((h2*)&X1)[2]; t3 = ((h2*)&X1)[3]; }      \
                if (P == 2) { t0 = ((h2*)&X2)[0]; t1 = ((h2*)&X2)[1];        \
                              t2 = ((h2*)&X2)[2]; t3 = ((h2*)&X2)[3]; }      \
                t0 = t0 + gr_h[P * 4 + 0]; t1 = t1 + gr_h[P * 4 + 1];        \
                t2 = t2 + gr_h[P * 4 + 2]; t3 = t3 + gr_h[P * 4 + 3];        \
                t0 = h2max(t0, t0 * c02); t1 = h2max(t1, t1 * c02);          \
                t2 = h2max(t2, t2 * c02); t3 = h2max(t3, t3 * c02);          \
                e[P] = FDOT2(t3, att_h[P * 4 + 3], FDOT2(t2, att_h[P * 4 + 2],\
                       FDOT2(t1, att_h[P * 4 + 1], FDOT2(t0, att_h[P * 4 + 0],\
                       0.f))));                                              \
            }                                                                \
            _Pragma("unroll")                                                \
            for (int d = 1; d < 8; d <<= 1) {                                \
                e[0] += __shfl_xor(e[0], d, 64);                             \
                e[1] += __shfl_xor(e[1], d, 64);                             \
                e[2] += __shfl_xor(e[2], d, 64);                             \
            }                                                                \
            if (active) {                                                    \
                _Pragma("unroll")                                            \
                for (int P = 0; P < 3; P++) {                                \
                    float mo = m[P];                                         \
                    float mn = fmaxf(mo, e[P]);                              \
                    float r  = fexp2(mo - mn);                               \
                    float p  = fexp2(e[P] - mn);                             \
                    m[P] = mn;                                               \
                    sden[P] = sden[P] * r + p;                               \
                    h2 r2 = pk2(r), p2 = pk2(p);                             \
                    const h2* xv = (P == 0) ? (const h2*)&X0                 \
                                 : (P == 1) ? (const h2*)&X1 : (const h2*)&X2;\
                    acc[P * 4 + 0] = acc[P * 4 + 0] * r2 + p2 * xv[0];       \
                    acc[P * 4 + 1] = acc[P * 4 + 1] * r2 + p2 * xv[1];       \
                    acc[P * 4 + 2] = acc[P * 4 + 2] * r2 + p2 * xv[2];       \
                    acc[P * 4 + 3] = acc[P * 4 + 3] * r2 + p2 * xv[3];       \
                }                                                            \
            }                                                                \
        }

        {
            LOADX(A0, A1, A2, lsrc(rp + g));
            int sN = lsrc(rp + 4 + g);
            int base = rp;
            for (;;) {
                LOADX(B0, B1, B2, sN);
                int sN2 = lsrc(base + 8 + g);
                PROC(A0, A1, A2, base);
                base += 4; if (base >= re) break;
                LOADX(A0, A1, A2, sN2);
                sN = lsrc(base + 8 + g);
                PROC(B0, B1, B2, base);
                base += 4; if (base >= re) break;
            }
        }
#undef PROC
#undef LOADX

        // merge the 4 group-partial states (butterfly over xor 16, 32)
        #pragma unroll
        for (int d = 16; d < 64; d <<= 1) {
            #pragma unroll
            for (int P = 0; P < 3; P++) {
                float mo = __shfl_xor(m[P], d, 64);
                float so = __shfl_xor(sden[P], d, 64);
                h2 ao0 = shfl_h2(acc[P * 4 + 0], d);
                h2 ao1 = shfl_h2(acc[P * 4 + 1], d);
                h2 ao2 = shfl_h2(acc[P * 4 + 2], d);
                h2 ao3 = shfl_h2(acc[P * 4 + 3], d);
                float mn = fmaxf(m[P], mo);
                float ra = exp2f(m[P] - mn);
                float rb = exp2f(mo - mn);
                sden[P] = sden[P] * ra + so * rb;
                h2 ra2 = pk2(ra), rb2 = pk2(rb);
                acc[P * 4 + 0] = acc[P * 4 + 0] * ra2 + ao0 * rb2;
                acc[P * 4 + 1] = acc[P * 4 + 1] * ra2 + ao1 * rb2;
                acc[P * 4 + 2] = acc[P * 4 + 2] * ra2 + ao2 * rb2;
                acc[P * 4 + 3] = acc[P * 4 + 3] * ra2 + ao3 * rb2;
                m[P] = mn;
            }
        }

        h2 iv[3];
        #pragma unroll
        for (int P = 0; P < 3; P++) {
            float inv = 1.0f / (sden[P] + 1e-16f);
            _Float16 ih = (_Float16)inv;
            iv[P] = (h2){ih, ih};
        }
        float of[8];
        #pragma unroll
        for (int j = 0; j < 4; j++) {
            h2 o = acc[0 * 4 + j] * iv[0] + acc[1 * 4 + j] * iv[1] + acc[2 * 4 + j] * iv[2];
            o = o + shfl_h2(o, 8);       // partner octet: other 3 heads
            of[2 * j]     = (float)o[0];
            of[2 * j + 1] = (float)o[1];
        }

        if (lane < 8) {                   // g==0, oct==0, q=lane
            f32x4 b0 = *(const f32x4*)(bias + q * 8);
            f32x4 b1 = *(const f32x4*)(bias + q * 8 + 4);
            f32x4 ov0, ov1;
            #pragma unroll
            for (int k = 0; k < 4; k++) {
                float v0 = of[k] * (1.0f / 6.0f) + b0[k];
                float v1 = of[k + 4] * (1.0f / 6.0f) + b1[k];
                ov0[k] = (v0 > 0.f) ? SELU_SCALE * v0
                                    : SELU_SCALE * SELU_ALPHA * (__expf(v0) - 1.0f);
                ov1[k] = (v1 > 0.f) ? SELU_SCALE * v1
                                    : SELU_SCALE * SELU_ALPHA * (__expf(v1) - 1.0f);
            }
            float* op = out + (size_t)node * 64 + q * 8;
            *(f32x4*)op = ov0;
            *(f32x4*)(op + 4) = ov1;
        }
    }
}

// ---------------- launch ----------------
extern "C" void kernel_launch(void* const* d_in, const int* in_sizes, int n_in,
                              void* d_out, int out_size, void* d_ws, size_t ws_size,
                              hipStream_t stream) {
    const float* x    = (const float*)d_in[0];
    const int*   eidx = (const int*)d_in[1];
    const float* Wl   = (const float*)d_in[2];
    const float* Wr   = (const float*)d_in[3];
    const float* att  = (const float*)d_in[4];
    const float* bias = (const float*)d_in[5];
    float* out = (float*)d_out;

    int n = in_sizes[0] / 64;        // nodes
    int E = in_sizes[1] / 2;         // edges (pre-self-loop)
    int Et = E + n;

    char* w = (char*)d_ws;
    size_t off = 0;
    auto carve = [&](size_t bytes) {
        void* p = w + off;
        off = (off + bytes + 255) & ~(size_t)255;
        return p;
    };
    _Float16* glr   = (_Float16*)carve((size_t)n * 768 * sizeof(_Float16));
    int* count      = (int*)carve((size_t)n * sizeof(int));
    int* row_ptr    = (int*)carve((size_t)(n + 1) * sizeof(int));
    int* cursor     = (int*)carve((size_t)n * sizeof(int));
    int* sorted_src = (int*)carve((size_t)Et * sizeof(int));
    int* blksum     = (int*)carve(64 * sizeof(int));
    (void)ws_size;

    int nb_n = (n + 255) / 256;
    int nb_e = (E + 255) / 256;
    int nblk = (n + 1023) / 1024;    // 49 for n=50000 (<= 64 required)

    hipMemsetAsync(count, 0, (size_t)n * sizeof(int), stream);
    hipLaunchKernelGGL(hist_kernel, dim3(nb_e), dim3(256), 0, stream, eidx, count, E);
    hipLaunchKernelGGL(scan_local_kernel, dim3(nblk), dim3(256), 0, stream,
                       count, row_ptr, blksum, n);
    hipLaunchKernelGGL(scan_blk_kernel, dim3(1), dim3(64), 0, stream,
                       blksum, row_ptr, nblk, n);
    hipLaunchKernelGGL(cursor_kernel, dim3(nb_n), dim3(256), 0, stream,
                       row_ptr, blksum, cursor, sorted_src, n);
    hipLaunchKernelGGL(scatter_kernel, dim3(nb_e), dim3(256), 0, stream,
                       eidx, cursor, sorted_src, E);
    hipLaunchKernelGGL(gemm_kernel, dim3((n + 63) / 64), dim3(256), 0, stream,
                       x, Wl, Wr, glr, n);
    hipLaunchKernelGGL(edge_kernel, dim3(2048), dim3(256), 0, stream,
                       glr, row_ptr, sorted_src, att, bias, out, n);
}